// Round 3
// baseline (454.649 us; speedup 1.0000x reference)
//
#include <hip/hip_runtime.h>

#define B_   512
#define C_   256
#define HWD_ 384

typedef __bf16 bf16x8 __attribute__((ext_vector_type(8)));
typedef float  f32x4  __attribute__((ext_vector_type(4)));

// chunk swizzle (involutive XOR on 16B-chunk index vs row) — spreads
// ds_read_b128 frag reads to ~2-way bank aliasing (free). Verified in R1 K3.
#define CSWZ(r) (((r) ^ ((r) >> 2)) & 3)

// ---------------- kernel 1: per-(b,c) mean over HWD=384 (verified baseline) ----
__global__ __launch_bounds__(256) void mean_kernel(const float* __restrict__ x,
                                                   float* __restrict__ cadj) {
    const int row  = (blockIdx.x << 2) + (threadIdx.x >> 6);
    const int lane = threadIdx.x & 63;
    const float2* p = (const float2*)(x + (size_t)row * HWD_);
    float s = 0.f;
#pragma unroll
    for (int t = 0; t < 3; ++t) {
        float2 v = p[lane + (t << 6)];
        s += v.x + v.y;
    }
#pragma unroll
    for (int off = 32; off; off >>= 1) s += __shfl_xor(s, off, 64);
    if (lane == 0) cadj[row] = s * (1.0f / HWD_);
}

// ---------------- kernel 2: fused GEMM, one block per (nt, b) ----------------
// M=256 (full), N=128 slice, K=256 in steps of 32. 512 threads = 8 waves (4m x 2n).
// x slice read exactly once per block (x read once chip-wide in this kernel),
// converted to bf16 in LDS. A = adj .* s built in-LDS from L2-hot adj + cadj.
__global__ __launch_bounds__(512) void gemm_fused(const float* __restrict__ x,
                                                  const float* __restrict__ adj,
                                                  const float* __restrict__ para,
                                                  const float* __restrict__ cadj,
                                                  float* __restrict__ out) {
    const int nt = blockIdx.x;   // 0..2
    const int b  = blockIdx.y;   // 0..511
    const int n0 = nt * 128;

    // As: row i (0..255), stride 64B; logical 16B chunk c (k-octet c) stored at c^CSWZ(i).
    // Bs: row n (0..127), stride 64B; same chunk rule. Chunk c holds k=8c..8c+7 (bf16).
    __shared__ __bf16 As[256 * 32];   // 16 KB
    __shared__ __bf16 Bs[128 * 32];   //  8 KB
    __shared__ float  ca_s[C_];       //  1 KB

    const int t    = threadIdx.x;
    const int lane = t & 63;
    const int w    = t >> 6;
    const int wm   = w & 3;          // 0..3  -> M rows wm*64..
    const int wn   = w >> 2;         // 0..1  -> N cols wn*64..
    const int lm   = lane & 15, quad = lane >> 4;

    if (t < C_) ca_s[t] = cadj[b * C_ + t];
    __syncthreads();

    // ---- A staging map: thread -> (row ai 0..255, 16-col half ah) ----
    const int ai = t >> 1, ah = t & 1;
    const float ca_i = ca_s[ai];
    const float* aglob = adj + (size_t)ai * C_ + ah * 16;
    char* arow = (char*)As + (size_t)ai * 64;
    const int asw = CSWZ(ai);
    char* adst0 = arow + (((2 * ah)     ^ asw) << 4);   // k-octet 2ah
    char* adst1 = arow + (((2 * ah + 1) ^ asw) << 4);   // k-octet 2ah+1

    // ---- B staging map: thread -> (k-octet kq8 0..3, n 0..127) ----
    const int kq8 = t >> 7, bn = t & 127;
    const float* bglob = x + (size_t)(b * C_ + 8 * kq8) * HWD_ + n0 + bn;
    char* bdst = (char*)Bs + (size_t)bn * 64 + ((kq8 ^ CSWZ(bn)) << 4);

    // ---- fragment read addresses (loop-invariant) ----
    const char* afp[4];
    const char* bfp[4];
#pragma unroll
    for (int mm = 0; mm < 4; ++mm) {
        const int ra = wm * 64 + mm * 16 + lm;
        afp[mm] = (const char*)As + (size_t)ra * 64 + ((quad ^ CSWZ(ra)) << 4);
    }
#pragma unroll
    for (int nn = 0; nn < 4; ++nn) {
        const int rb = wn * 64 + nn * 16 + lm;
        bfp[nn] = (const char*)Bs + (size_t)rb * 64 + ((quad ^ CSWZ(rb)) << 4);
    }

    f32x4 acc[4][4];
#pragma unroll
    for (int mm = 0; mm < 4; ++mm)
#pragma unroll
        for (int nn = 0; nn < 4; ++nn)
            acc[mm][nn] = (f32x4){0.f, 0.f, 0.f, 0.f};

    for (int k0 = 0; k0 < C_; k0 += 32) {
        __syncthreads();   // protect previous iteration's fragment reads
        // ---- stage A = adj .* s : rows 0..255 x cols k0..k0+31 ----
        {
            const float* ap = aglob + k0;
            float4 av[4];
#pragma unroll
            for (int q = 0; q < 4; ++q) av[q] = ((const float4*)ap)[q];
            bf16x8 pk0, pk1;
#pragma unroll
            for (int jj = 0; jj < 16; ++jj) {
                float aval = ((const float*)av)[jj];
                float d  = ca_s[k0 + ah * 16 + jj] - ca_i;
                float tt = __expf(-fabsf(d));
                float s  = 2.f * tt / (1.f + tt);
                float v  = aval * s;
                if (jj < 8) pk0[jj & 7] = (__bf16)v;
                else        pk1[jj & 7] = (__bf16)v;
            }
            *(bf16x8*)adst0 = pk0;
            *(bf16x8*)adst1 = pk1;
        }
        // ---- stage B: x[k0+8kq8 .. +7][n0+bn] -> one b128 per thread ----
        {
            float f[8];
#pragma unroll
            for (int j = 0; j < 8; ++j)
                f[j] = bglob[(size_t)(k0 + j) * HWD_];   // coalesced across bn lanes
            bf16x8 pk;
#pragma unroll
            for (int j = 0; j < 8; ++j) pk[j] = (__bf16)f[j];
            *(bf16x8*)bdst = pk;
        }
        __syncthreads();
        // ---- fragment loads (single swizzled b128 each) + 32 mfma ----
        bf16x8 af[4], bfr[4];
#pragma unroll
        for (int mm = 0; mm < 4; ++mm) af[mm]  = *(const bf16x8*)afp[mm];
#pragma unroll
        for (int nn = 0; nn < 4; ++nn) bfr[nn] = *(const bf16x8*)bfp[nn];
#pragma unroll
        for (int mm = 0; mm < 4; ++mm)
#pragma unroll
            for (int nn = 0; nn < 4; ++nn)
                acc[mm][nn] = __builtin_amdgcn_mfma_f32_16x16x32_bf16(
                    af[mm], bfr[nn], acc[mm][nn], 0, 0, 0);
    }

    // ---- epilogue: *para, relu, store (mapping identical to verified baseline) ----
#pragma unroll
    for (int mm = 0; mm < 4; ++mm) {
#pragma unroll
        for (int r = 0; r < 4; ++r) {
            const int i = wm * 64 + mm * 16 + quad * 4 + r;
            const float* pp = para + (size_t)i * HWD_ + n0;
            float* op = out + ((size_t)b * C_ + i) * HWD_ + n0;
#pragma unroll
            for (int nn = 0; nn < 4; ++nn) {
                const int n = wn * 64 + nn * 16 + lm;
                float v = acc[mm][nn][r] * pp[n];
                op[n] = v > 0.f ? v : 0.f;
            }
        }
    }
}

extern "C" void kernel_launch(void* const* d_in, const int* in_sizes, int n_in,
                              void* d_out, int out_size, void* d_ws, size_t ws_size,
                              hipStream_t stream) {
    const float* x    = (const float*)d_in[0];
    const float* adj  = (const float*)d_in[1];
    const float* para = (const float*)d_in[2];
    float* out  = (float*)d_out;
    float* cadj = (float*)d_ws;   // 512*256 floats = 512 KB

    mean_kernel<<<dim3((B_ * C_) / 4), 256, 0, stream>>>(x, cadj);
    gemm_fused<<<dim3(3, B_), 512, 0, stream>>>(x, adj, para, cadj, out);
}

// Round 4
// 404.155 us; speedup vs baseline: 1.1249x; 1.1249x over previous
//
#include <hip/hip_runtime.h>

#define B_   512
#define C_   256
#define HWD_ 384

typedef __bf16 bf16x8 __attribute__((ext_vector_type(8)));
typedef float  f32x4  __attribute__((ext_vector_type(4)));

// chunk swizzle (involutive XOR on 16B-chunk index vs row) — spreads
// ds_read_b128 frag reads to ~2-way bank aliasing (free). Verified R1/R3.
#define CSWZ(r) (((r) ^ ((r) >> 2)) & 3)

// ---------------- kernel 1: per-(b,c) mean over HWD=384 (verified) ----------
__global__ __launch_bounds__(256) void mean_kernel(const float* __restrict__ x,
                                                   float* __restrict__ cadj) {
    const int row  = (blockIdx.x << 2) + (threadIdx.x >> 6);
    const int lane = threadIdx.x & 63;
    const float2* p = (const float2*)(x + (size_t)row * HWD_);
    float s = 0.f;
#pragma unroll
    for (int t = 0; t < 3; ++t) {
        float2 v = p[lane + (t << 6)];
        s += v.x + v.y;
    }
#pragma unroll
    for (int off = 32; off; off >>= 1) s += __shfl_xor(s, off, 64);
    if (lane == 0) cadj[row] = s * (1.0f / HWD_);
}

// ---------------- kernel 2: fused GEMM, software-pipelined ------------------
// One block per (nt, b): M=256 full, N=128 slice, K=256 in 8 steps of 32.
// 512 threads = 8 waves (4m x 2n). Raw global loads for step s+1 are issued
// at the top of step s (reg-destined: no barrier drain), hiding HBM/L3
// latency under the current step's convert+MFMA.
__global__ __launch_bounds__(512) void gemm_fused(const float* __restrict__ x,
                                                  const float* __restrict__ adj,
                                                  const float* __restrict__ para,
                                                  const float* __restrict__ cadj,
                                                  float* __restrict__ out) {
    const int nt = blockIdx.x;   // 0..2
    const int b  = blockIdx.y;   // 0..511
    const int n0 = nt * 128;

    // As: row i (0..255), stride 64B; logical 16B chunk c stored at c^CSWZ(i).
    // Bs: row n (0..127), stride 64B; same rule. Chunk c holds k=8c..8c+7.
    __shared__ __bf16 As[256 * 32];   // 16 KB
    __shared__ __bf16 Bs[128 * 32];   //  8 KB
    __shared__ float  ca_s[C_];       //  1 KB

    const int t    = threadIdx.x;
    const int lane = t & 63;
    const int w    = t >> 6;
    const int wm   = w & 3;          // 0..3 -> M rows wm*64..
    const int wn   = w >> 2;         // 0..1 -> N cols wn*64..
    const int lm   = lane & 15, quad = lane >> 4;

    if (t < C_) ca_s[t] = cadj[b * C_ + t];

    // ---- A staging map: thread -> (row ai 0..255, 16-col half ah) ----
    const int ai = t >> 1, ah = t & 1;
    const float* aglob = adj + (size_t)ai * C_ + ah * 16;
    char* arow = (char*)As + (size_t)ai * 64;
    const int asw = CSWZ(ai);
    char* adst0 = arow + (((2 * ah)     ^ asw) << 4);
    char* adst1 = arow + (((2 * ah + 1) ^ asw) << 4);

    // ---- B staging map: thread -> (k-octet kq8 0..3, n 0..127) ----
    const int kq8 = t >> 7, bn = t & 127;
    const float* bglob = x + (size_t)(b * C_ + 8 * kq8) * HWD_ + n0 + bn;
    char* bdst = (char*)Bs + (size_t)bn * 64 + ((kq8 ^ CSWZ(bn)) << 4);

    // ---- fragment read addresses (loop-invariant) ----
    const char* afp[4];
    const char* bfp[4];
#pragma unroll
    for (int mm = 0; mm < 4; ++mm) {
        const int ra = wm * 64 + mm * 16 + lm;
        afp[mm] = (const char*)As + (size_t)ra * 64 + ((quad ^ CSWZ(ra)) << 4);
    }
#pragma unroll
    for (int nn = 0; nn < 4; ++nn) {
        const int rb = wn * 64 + nn * 16 + lm;
        bfp[nn] = (const char*)Bs + (size_t)rb * 64 + ((quad ^ CSWZ(rb)) << 4);
    }

    __syncthreads();                 // ca_s visible
    const float ca_i = ca_s[ai];

    // ---- prologue: raw-load tile 0 into registers ----
    float4 avc[4];
    float  fbc[8];
#pragma unroll
    for (int q = 0; q < 4; ++q) avc[q] = ((const float4*)aglob)[q];
#pragma unroll
    for (int j = 0; j < 8; ++j)  fbc[j] = bglob[(size_t)j * HWD_];

    f32x4 acc[4][4];
#pragma unroll
    for (int mm = 0; mm < 4; ++mm)
#pragma unroll
        for (int nn = 0; nn < 4; ++nn)
            acc[mm][nn] = (f32x4){0.f, 0.f, 0.f, 0.f};

#pragma unroll
    for (int s = 0; s < 8; ++s) {
        const int k0 = s * 32;

        // 1) issue next tile's raw loads (async; consumed next iteration)
        float4 avn[4];
        float  fbn[8];
        if (s < 7) {
#pragma unroll
            for (int q = 0; q < 4; ++q)
                avn[q] = ((const float4*)(aglob + k0 + 32))[q];
#pragma unroll
            for (int j = 0; j < 8; ++j)
                fbn[j] = bglob[(size_t)(k0 + 32 + j) * HWD_];
        }

        // 2) convert current tile and store to LDS
        bf16x8 pk0, pk1;
        {
            const float* cah = &ca_s[k0 + ah * 16];
#pragma unroll
            for (int jj = 0; jj < 16; ++jj) {
                float aval = ((const float*)avc)[jj];
                float d  = cah[jj] - ca_i;
                float tt = __expf(-fabsf(d));
                float sg = 2.f * tt * __builtin_amdgcn_rcpf(1.f + tt);
                float v  = aval * sg;
                if (jj < 8) pk0[jj & 7] = (__bf16)v;
                else        pk1[jj & 7] = (__bf16)v;
            }
        }
        bf16x8 pkB;
#pragma unroll
        for (int j = 0; j < 8; ++j) pkB[j] = (__bf16)fbc[j];
        *(bf16x8*)adst0 = pk0;
        *(bf16x8*)adst1 = pk1;
        *(bf16x8*)bdst  = pkB;
        __syncthreads();

        // 3) fragment loads (single swizzled b128 each) + 16 mfma
        bf16x8 af[4], bfr[4];
#pragma unroll
        for (int mm = 0; mm < 4; ++mm) af[mm]  = *(const bf16x8*)afp[mm];
#pragma unroll
        for (int nn = 0; nn < 4; ++nn) bfr[nn] = *(const bf16x8*)bfp[nn];
        __builtin_amdgcn_s_setprio(1);
#pragma unroll
        for (int mm = 0; mm < 4; ++mm)
#pragma unroll
            for (int nn = 0; nn < 4; ++nn)
                acc[mm][nn] = __builtin_amdgcn_mfma_f32_16x16x32_bf16(
                    af[mm], bfr[nn], acc[mm][nn], 0, 0, 0);
        __builtin_amdgcn_s_setprio(0);
        __syncthreads();             // LDS free for next iteration's writes

        // 4) rotate prefetch registers
        if (s < 7) {
#pragma unroll
            for (int q = 0; q < 4; ++q) avc[q] = avn[q];
#pragma unroll
            for (int j = 0; j < 8; ++j)  fbc[j] = fbn[j];
        }
    }

    // ---- epilogue: *para, relu, store (verified mapping) ----
#pragma unroll
    for (int mm = 0; mm < 4; ++mm) {
#pragma unroll
        for (int r = 0; r < 4; ++r) {
            const int i = wm * 64 + mm * 16 + quad * 4 + r;
            const float* pp = para + (size_t)i * HWD_ + n0;
            float* op = out + ((size_t)b * C_ + i) * HWD_ + n0;
#pragma unroll
            for (int nn = 0; nn < 4; ++nn) {
                const int n = wn * 64 + nn * 16 + lm;
                float v = acc[mm][nn][r] * pp[n];
                op[n] = v > 0.f ? v : 0.f;
            }
        }
    }
}

extern "C" void kernel_launch(void* const* d_in, const int* in_sizes, int n_in,
                              void* d_out, int out_size, void* d_ws, size_t ws_size,
                              hipStream_t stream) {
    const float* x    = (const float*)d_in[0];
    const float* adj  = (const float*)d_in[1];
    const float* para = (const float*)d_in[2];
    float* out  = (float*)d_out;
    float* cadj = (float*)d_ws;   // 512*256 floats = 512 KB

    mean_kernel<<<dim3((B_ * C_) / 4), 256, 0, stream>>>(x, cadj);
    gemm_fused<<<dim3(3, B_), 512, 0, stream>>>(x, adj, para, cadj, out);
}